// Round 8
// baseline (1006.309 us; speedup 1.0000x reference)
//
#include <hip/hip_runtime.h>
#include <hip/hip_bf16.h>

// Problem constants (fixed by setup_inputs)
constexpr int T_ = 4, B_ = 8, N_ = 1024, C_ = 512, H_ = 8, D_ = 64;
constexpr int M_ = 8192;             // rows per timestep
constexpr int MT_ = 32768;           // T*M
constexpr int K_ = 512;

#define TAU_INV 0.5f
#define V_TH    1.0f
#define BN_EPS  1e-5f

typedef __attribute__((ext_vector_type(2))) float f32x2;

// ---- packed fp32 FMA: two independent scalar-FMA-bitexact ops -------------
// even j: b operand is LO half of bp  -> both halves use src1.lo
#define PK_EVEN(acc, a, b) \
  asm("v_pk_fma_f32 %0, %1, %2, %0 op_sel_hi:[1,0,1]" \
      : "+v"(acc) : "v"(a), "v"(b))
// odd j: b operand is HI half of bp   -> both halves use src1.hi
#define PK_ODD(acc, a, b) \
  asm("v_pk_fma_f32 %0, %1, %2, %0 op_sel:[0,1,0]" \
      : "+v"(acc) : "v"(a), "v"(b))

// ---- load 4 consecutive elements as float4 --------------------------------
__device__ __forceinline__ float4 ldf4(const float* p) {
  return *(const float4*)p;
}
__device__ __forceinline__ float4 ldf4(const __hip_bfloat16* p) {
  const ushort4 u = *(const ushort4*)p;
  float4 v;
  v.x = __bfloat162float(*(const __hip_bfloat16*)&u.x);
  v.y = __bfloat162float(*(const __hip_bfloat16*)&u.y);
  v.z = __bfloat162float(*(const __hip_bfloat16*)&u.z);
  v.w = __bfloat162float(*(const __hip_bfloat16*)&u.w);
  return v;
}
__device__ __forceinline__ void ld4(const float* p, float* d) {
  const float4 v = *(const float4*)p;
  d[0] = v.x; d[1] = v.y; d[2] = v.z; d[3] = v.w;
}
// ---- store 4 consecutive values -------------------------------------------
__device__ __forceinline__ void st4(__hip_bfloat16* p, const float* s) {
  ushort4 u;
  *(__hip_bfloat16*)&u.x = __float2bfloat16(s[0]);
  *(__hip_bfloat16*)&u.y = __float2bfloat16(s[1]);
  *(__hip_bfloat16*)&u.z = __float2bfloat16(s[2]);
  *(__hip_bfloat16*)&u.w = __float2bfloat16(s[3]);
  *(ushort4*)p = u;
}
__device__ __forceinline__ void st4(float* p, const float* s) {
  *(float4*)p = make_float4(s[0], s[1], s[2], s[3]);
}

// ---- async global->LDS, 16B per lane (HW scatters lane*16 from wave base) --
__device__ __forceinline__ void dma16(const void* g, void* l) {
  __builtin_amdgcn_global_load_lds(
      (const __attribute__((address_space(1))) unsigned int*)g,
      (__attribute__((address_space(3))) unsigned int*)l, 16, 0, 0);
}

// ---------------------------------------------------------------------------
// W transpose: Wt[w][k][d] = W[w][d][k]  (k-major rows for DMA staging).
// ---------------------------------------------------------------------------
struct WPtrs { const float* W[4]; };

__global__ __launch_bounds__(256) void transpose_w(WPtrs wp, float* __restrict__ Wt)
{
  __shared__ float tile[32][33];
  const int w = blockIdx.z;
  const float* __restrict__ W = wp.W[w];
  float* __restrict__ dst = Wt + (size_t)w * K_ * C_;
  const int k0 = blockIdx.x * 32, d0 = blockIdx.y * 32;
  const int tx = threadIdx.x, ty = threadIdx.y;   // 32 x 8
#pragma unroll
  for (int i = 0; i < 32; i += 8)
    tile[ty + i][tx] = W[(size_t)(d0 + ty + i) * K_ + k0 + tx];
  __syncthreads();
#pragma unroll
  for (int i = 0; i < 32; i += 8)
    dst[(size_t)(k0 + ty + i) * C_ + d0 + tx] = tile[tx][ty + i];
}

// ---------------------------------------------------------------------------
// x transpose: XT[k][m*4 + t] = x[t][m][k]   (k-major, t-interleaved rows).
// ---------------------------------------------------------------------------
__global__ __launch_bounds__(256) void transpose_x(
    const float* __restrict__ x, float* __restrict__ XT)
{
  __shared__ float tile[32][132];
  const int bk = blockIdx.x * 32, bm = blockIdx.y * 32;
  const int tx = threadIdx.x & 31, ty = threadIdx.x >> 5;   // 32 x 8
#pragma unroll
  for (int t = 0; t < T_; ++t)
#pragma unroll
    for (int i = 0; i < 4; ++i) {
      const int m = ty + 8 * i;
      tile[tx][m * 4 + t] = x[((size_t)t * M_ + bm + m) * K_ + bk + tx];
    }
  __syncthreads();
  const int k = threadIdx.x >> 3, q = threadIdx.x & 7;
#pragma unroll
  for (int u = 0; u < 4; ++u)
    st4(&XT[(size_t)(bk + k) * MT_ + bm * 4 + q * 16 + u * 4],
        &tile[k][q * 16 + u * 4]);
}

// ---------------------------------------------------------------------------
// Fused GEMM (+bias +BN +in-register multi-step LIF) -> spike tensor (T,M,C).
// BIT-EXACTNESS CONTRACT: each output's k-summation is a single dedicated
// fp32 accumulator over k = 0..511 STRICTLY ASCENDING; bias/BN/LIF
// expressions textually identical to all prior passing rounds (absmax 0.0).
// v_pk_fma_f32 halves are bitwise-identical scalar FMAs (packing over the
// t-dimension; b broadcast via VOP3P op_sel half-select) — order unchanged.
//
// Tile: 128 "rows" x 256 cols where rows = (32 m) x (4 t interleaved).
// Staging: pure global_load_lds 16B/lane from k-major XT / Wt (R7-proven).
// ---------------------------------------------------------------------------
template <typename TIn, typename TOut>
struct GArgs {
  const TIn* AT;             // [K][MT] t-interleaved k-major input
  const float* Wt[3];        // [K][C]
  const float* bias[3];
  const float* bn[3];
  TOut* S[3];                // (T, M, C) spikes
};

template <typename TIn, typename TOut>
__global__ __launch_bounds__(256, 2) void gemm_lif(GArgs<TIn, TOut> args)
{
  constexpr int BK = 32;
  constexpr bool BF = (sizeof(TIn) == 2);
  __shared__ __align__(16) TIn  As[BK * 128];
  __shared__ __align__(16) float Bs[BK * 256];

  const int z = blockIdx.z;
  const TIn*   __restrict__ AT   = args.AT;
  const float* __restrict__ Wt   = args.Wt[z];
  const float* __restrict__ bias = args.bias[z];
  const float* __restrict__ bnp  = args.bn[z];
  TOut*        __restrict__ S    = args.S[z];

  const int tid  = threadIdx.x;
  const int lane = tid & 63;
  const int wave = __builtin_amdgcn_readfirstlane(tid >> 6);
  const int tx = tid & 15, ty = tid >> 4;
  const int bm_m = blockIdx.y * 32;       // m-tile base
  const int bm4  = bm_m * 4;              // word base within a k-row of AT
  const int bn0  = blockIdx.x * 256;

  // acc2[g][h][p][j] = {acc[t=2p][j], acc[t=2p+1][j]}
  f32x2 acc2[2][4][2][4];
#pragma unroll
  for (int g = 0; g < 2; ++g)
#pragma unroll
    for (int h = 0; h < 4; ++h)
#pragma unroll
      for (int p = 0; p < 2; ++p)
#pragma unroll
        for (int j = 0; j < 4; ++j) acc2[g][h][p][j] = (f32x2){0.0f, 0.0f};

  for (int k0 = 0; k0 < K_; k0 += BK) {
    // ---- DMA-stage A tile (BK x 128 elems) -------------------------------
    if constexpr (!BF) {
#pragma unroll
      for (int c = 0; c < 4; ++c) {
        const int ins = wave * 4 + c;                 // 0..15, 2 kk-rows each
        const int kk = ins * 2 + (lane >> 5);
        dma16(AT + (size_t)(k0 + kk) * MT_ + bm4 + (lane & 31) * 4,
              (void*)((float*)As + ins * 256));
      }
    } else {
#pragma unroll
      for (int c = 0; c < 2; ++c) {
        const int ins = wave * 2 + c;                 // 0..7, 4 kk-rows each
        const int kk = ins * 4 + (lane >> 4);
        dma16(AT + (size_t)(k0 + kk) * MT_ + bm4 + (lane & 15) * 8,
              (void*)((TIn*)As + ins * 512));
      }
    }
    // ---- DMA-stage B tile (BK x 256 floats) ------------------------------
#pragma unroll
    for (int c = 0; c < 8; ++c) {
      const int ins = wave * 8 + c;                   // 0..31, 1 kk-row each
      dma16(Wt + (size_t)(k0 + ins) * C_ + bn0 + lane * 4,
            (void*)(Bs + ins * 256));
    }
    __syncthreads();                                  // drains vmcnt

    // ---- hot loop: k strictly ascending ----------------------------------
#pragma unroll
    for (int kk = 0; kk < BK; ++kk) {
      f32x2 aP[2][2], bP[4][2];
#pragma unroll
      for (int g = 0; g < 2; ++g) {
        const float4 av = ldf4((const TIn*)As + kk * 128 + ty * 4 + 64 * g);
        aP[g][0] = (f32x2){av.x, av.y};
        aP[g][1] = (f32x2){av.z, av.w};
      }
#pragma unroll
      for (int h = 0; h < 4; ++h) {
        const float4 bv = ldf4(Bs + kk * 256 + tx * 4 + 64 * h);
        bP[h][0] = (f32x2){bv.x, bv.y};
        bP[h][1] = (f32x2){bv.z, bv.w};
      }
#pragma unroll
      for (int g = 0; g < 2; ++g)
#pragma unroll
        for (int h = 0; h < 4; ++h)
#pragma unroll
          for (int p = 0; p < 2; ++p) {
            PK_EVEN(acc2[g][h][p][0], aP[g][p], bP[h][0]);
            PK_ODD (acc2[g][h][p][1], aP[g][p], bP[h][0]);
            PK_EVEN(acc2[g][h][p][2], aP[g][p], bP[h][1]);
            PK_ODD (acc2[g][h][p][3], aP[g][p], bP[h][1]);
          }
    }
    __syncthreads();
  }

  // ---- epilogue: bias -> BN -> in-register LIF over t --------------------
#pragma unroll
  for (int h = 0; h < 4; ++h) {
    const int d = bn0 + tx * 4 + 64 * h;
    float bi[4], gg[4], be[4], mu[4], vv[4];
    ld4(&bias[d], bi);
    ld4(&bnp[d], gg);
    ld4(&bnp[C_ + d], be);
    ld4(&bnp[2 * C_ + d], mu);
    ld4(&bnp[3 * C_ + d], vv);
    float inv[4];
#pragma unroll
    for (int j = 0; j < 4; ++j) inv[j] = 1.0f / sqrtf(vv[j] + BN_EPS);
#pragma unroll
    for (int g = 0; g < 2; ++g) {
      const int m = bm_m + ty + 16 * g;
      float sv[4][4];                       // [t][j]
#pragma unroll
      for (int j = 0; j < 4; ++j) {
        float mm = 0.0f;
#pragma unroll
        for (int t = 0; t < 4; ++t) {
          float y = acc2[g][h][t >> 1][j][t & 1] + bi[j];
          y = (y - mu[j]) * inv[j] * gg[j] + be[j];
          float m2 = mm + (y - mm) * TAU_INV;
          float s = (m2 - V_TH >= 0.0f) ? 1.0f : 0.0f;
          sv[t][j] = s;
          mm = (s != 0.0f) ? 0.0f : m2;
        }
      }
#pragma unroll
      for (int t = 0; t < 4; ++t)
        st4(&S[((size_t)t * M_ + m) * C_ + d], sv[t]);
    }
  }
}

// ---------------------------------------------------------------------------
// LIF + transpose: Y (t,m,c) fp32 -> AT[c][m*4+t] bf16 (proj GEMM input).
// Identical LIF expressions (absmax 0.0 contract).
// ---------------------------------------------------------------------------
__global__ __launch_bounds__(256) void lif_T(
    const float* __restrict__ Y, __hip_bfloat16* __restrict__ AT)
{
  __shared__ __hip_bfloat16 lds[64][72];   // [c][(m&15)*4+t], 144B rows
  const int bm = blockIdx.x * 16, bc = blockIdx.y * 64;
  const int tid = threadIdx.x;
  const int mm = tid >> 4, c4 = (tid & 15) * 4;
  float mem[4] = {0.0f, 0.0f, 0.0f, 0.0f};
#pragma unroll
  for (int t = 0; t < T_; ++t) {
    float y[4];
    ld4(&Y[((size_t)t * M_ + bm + mm) * C_ + bc + c4], y);
#pragma unroll
    for (int j = 0; j < 4; ++j) {
      float m2 = mem[j] + (y[j] - mem[j]) * TAU_INV;
      float s = (m2 - V_TH >= 0.0f) ? 1.0f : 0.0f;
      lds[c4 + j][mm * 4 + t] = __float2bfloat16(s);
      mem[j] = (s != 0.0f) ? 0.0f : m2;
    }
  }
  __syncthreads();
  const int c = tid >> 2, q = tid & 3;
  *(uint4*)(AT + (size_t)(bc + c) * MT_ + bm * 4 + q * 16) =
      *(const uint4*)&lds[c][q * 16];
}

// ---------------------------------------------------------------------------
// Linear attention per (t,b,h): kv = k^T v / N (64x64), y = q @ kv (1024x64).
// Spikes are {0,1}: all arithmetic here is EXACT in fp32 regardless of order.
// ---------------------------------------------------------------------------
__global__ __launch_bounds__(256) void attn_kernel(
    const __hip_bfloat16* __restrict__ Q,
    const __hip_bfloat16* __restrict__ Kk,
    const __hip_bfloat16* __restrict__ V,
    float* __restrict__ Y)
{
  __shared__ float s1[64][65];
  __shared__ float s2[64][65];
  __shared__ float kv[64][65];
  const int tid = threadIdx.x;
  const int h = blockIdx.x, b = blockIdx.y, t = blockIdx.z;
  const size_t base = ((size_t)t * B_ + b) * (size_t)N_ * C_ + (size_t)h * D_;
  const int d0 = (tid >> 4) * 4;
  const int e0 = (tid & 15) * 4;

  float acc[4][4];
#pragma unroll
  for (int i = 0; i < 4; ++i)
#pragma unroll
    for (int j = 0; j < 4; ++j) acc[i][j] = 0.0f;

  for (int nc = 0; nc < N_; nc += 64) {
#pragma unroll
    for (int i = 0; i < 16; ++i) {
      int idx = tid + i * 256;
      int r = idx >> 6, c = idx & 63;
      s1[r][c] = __bfloat162float(Kk[base + (size_t)(nc + r) * C_ + c]);
      s2[r][c] = __bfloat162float(V[base + (size_t)(nc + r) * C_ + c]);
    }
    __syncthreads();
#pragma unroll
    for (int nn = 0; nn < 64; ++nn) {
      float a[4], bb[4];
#pragma unroll
      for (int i = 0; i < 4; ++i) a[i] = s1[nn][d0 + i];
#pragma unroll
      for (int j = 0; j < 4; ++j) bb[j] = s2[nn][e0 + j];
#pragma unroll
      for (int i = 0; i < 4; ++i)
#pragma unroll
        for (int j = 0; j < 4; ++j) acc[i][j] += a[i] * bb[j];
    }
    __syncthreads();
  }
#pragma unroll
  for (int i = 0; i < 4; ++i)
#pragma unroll
    for (int j = 0; j < 4; ++j)
      kv[d0 + i][e0 + j] = acc[i][j] * (1.0f / (float)N_);
  __syncthreads();

  for (int rc = 0; rc < N_; rc += 64) {
#pragma unroll
    for (int i = 0; i < 16; ++i) {
      int idx = tid + i * 256;
      int r = idx >> 6, c = idx & 63;
      s1[r][c] = __bfloat162float(Q[base + (size_t)(rc + r) * C_ + c]);
    }
    __syncthreads();
    float o[4][4];
#pragma unroll
    for (int i = 0; i < 4; ++i)
#pragma unroll
      for (int j = 0; j < 4; ++j) o[i][j] = 0.0f;
#pragma unroll
    for (int d = 0; d < 64; ++d) {
      float a[4], bb[4];
#pragma unroll
      for (int i = 0; i < 4; ++i) a[i] = s1[d0 + i][d];
#pragma unroll
      for (int j = 0; j < 4; ++j) bb[j] = kv[d][e0 + j];
#pragma unroll
      for (int i = 0; i < 4; ++i)
#pragma unroll
        for (int j = 0; j < 4; ++j) o[i][j] += a[i] * bb[j];
    }
#pragma unroll
    for (int i = 0; i < 4; ++i)
#pragma unroll
      for (int j = 0; j < 4; ++j)
        Y[base + (size_t)(rc + d0 + i) * C_ + e0 + j] = o[i][j];
    __syncthreads();
  }
}

extern "C" void kernel_launch(void* const* d_in, const int* in_sizes, int n_in,
                              void* d_out, int out_size, void* d_ws, size_t ws_size,
                              hipStream_t stream)
{
  const float* x   = (const float*)d_in[0];
  const float* Wq  = (const float*)d_in[1];
  const float* bq  = (const float*)d_in[2];
  const float* Wk  = (const float*)d_in[3];
  const float* bk  = (const float*)d_in[4];
  const float* Wv  = (const float*)d_in[5];
  const float* bv  = (const float*)d_in[6];
  const float* Wp  = (const float*)d_in[7];
  const float* bp  = (const float*)d_in[8];
  const float* bnp = (const float*)d_in[9];   // (4 layers, 4, C)
  float* out = (float*)d_out;

  char* ws = (char*)d_ws;
  float* XT = (float*)ws;  ws += (size_t)K_ * MT_ * sizeof(float);     // 64 MB
  float* Wt = (float*)ws;  ws += (size_t)4 * K_ * C_ * sizeof(float);  //  4 MB
  __hip_bfloat16* q_s = (__hip_bfloat16*)ws; ws += (size_t)MT_ * C_ * 2;
  __hip_bfloat16* k_s = (__hip_bfloat16*)ws; ws += (size_t)MT_ * C_ * 2;
  __hip_bfloat16* v_s = (__hip_bfloat16*)ws; ws += (size_t)MT_ * C_ * 2;
  float* Y = XT;               // alias: XT dead after qkv GEMMs
  __hip_bfloat16* aT = q_s;    // alias: q_s dead after attn; same size

  // ---- one-time per-launch transposes ------------------------------------
  WPtrs wp; wp.W[0] = Wq; wp.W[1] = Wk; wp.W[2] = Wv; wp.W[3] = Wp;
  transpose_w<<<dim3(K_ / 32, C_ / 32, 4), dim3(32, 8), 0, stream>>>(wp, Wt);
  transpose_x<<<dim3(K_ / 32, M_ / 32), 256, 0, stream>>>(x, XT);

  // ---- fused q,k,v GEMM+BN+LIF (one dispatch, z = weight) ----------------
  GArgs<float, __hip_bfloat16> qa;
  qa.AT = XT;
  qa.Wt[0] = Wt; qa.Wt[1] = Wt + (size_t)K_ * C_; qa.Wt[2] = Wt + (size_t)2 * K_ * C_;
  qa.bias[0] = bq; qa.bias[1] = bk; qa.bias[2] = bv;
  qa.bn[0] = bnp + 0 * 4 * C_;
  qa.bn[1] = bnp + 1 * 4 * C_;
  qa.bn[2] = bnp + 2 * 4 * C_;
  qa.S[0] = q_s; qa.S[1] = k_s; qa.S[2] = v_s;
  gemm_lif<float, __hip_bfloat16>
      <<<dim3(C_ / 256, M_ / 32, 3), 256, 0, stream>>>(qa);

  // ---- attention (exact) -> Y, then LIF+transpose -> aT ------------------
  attn_kernel<<<dim3(H_, B_, T_), 256, 0, stream>>>(q_s, k_s, v_s, Y);
  lif_T<<<dim3(M_ / 16, C_ / 64), 256, 0, stream>>>(Y, aT);

  // ---- proj GEMM+BN+LIF -> out (fp32 spikes) -----------------------------
  GArgs<__hip_bfloat16, float> pa;
  pa.AT = aT;
  pa.Wt[0] = Wt + (size_t)3 * K_ * C_;
  pa.bias[0] = bp;
  pa.bn[0] = bnp + 3 * 4 * C_;
  pa.S[0] = out;
  gemm_lif<__hip_bfloat16, float>
      <<<dim3(C_ / 256, M_ / 32, 1), 256, 0, stream>>>(pa);
}